// Round 3
// baseline (20.356 us; speedup 1.0000x reference)
//
#include <hip/hip_runtime.h>
#include <math.h>

// ---------------------------------------------------------------------------
// TripletLossAttribute — fully fused, one kernel + one 4B memset.
//   seg(k): k in [341*d, 341*(d+1)) for d<5, seg5 = [1705, 2048)
//   sq[i,j]  = sum_k a2[i,j,seg(k)] * (x_j[k]-x_i[k])^2
//   dist     = sqrt(max(sq, 1e-12))
//   ap[i] = max_{t_j==t_i} dist;  an[i] = min_{t_j!=t_i} dist
//   loss = mean(relu(ap - an + 0.3))
//
// Grid: 256 blocks (b = i*4 + jc), 256 threads (4 waves). Wave w computes
// pairs (i, jc*16 + w*4 .. +3) with x_i held in registers. Block reduces its
// 16 dists to a masked (pmax, pmin) partial -> ws via device-scope atomicExch
// (performed at the coherent point, so no cross-XCD L2 staleness), then
// last-arriving block combines 64 rows x 4 partials and writes the loss.
//
// ws layout: float pm[512] (pmax,pmin per block at [2b],[2b+1]);
//            int counter at byte offset 2048 (zeroed by memsetAsync per call).
// ---------------------------------------------------------------------------

__global__ __launch_bounds__(256) void triplet_fused(
    const float* __restrict__ x,     // 64 x 2048
    const int*   __restrict__ tgt,   // 64
    const float* __restrict__ attr,  // 64 x 64 x 6
    float*       __restrict__ out,   // 1
    float*       __restrict__ ws)    // scratch (see layout above)
{
    const int b    = blockIdx.x;     // i*4 + jc
    const int i    = b >> 2;
    const int jc   = b & 3;
    const int lane = threadIdx.x & 63;
    const int wave = threadIdx.x >> 6;

    __shared__ float sm[16];
    __shared__ int   s_last;

    // x_i row staged in registers: 8 x float4 per lane (coalesced)
    const float4* __restrict__ xip = (const float4*)(x + i * 2048);
    const float4 xr0 = xip[0 * 64 + lane], xr1 = xip[1 * 64 + lane],
                 xr2 = xip[2 * 64 + lane], xr3 = xip[3 * 64 + lane],
                 xr4 = xip[4 * 64 + lane], xr5 = xip[5 * 64 + lane],
                 xr6 = xip[6 * 64 + lane], xr7 = xip[7 * 64 + lane];

    const int ti    = tgt[i];
    const int jbase = jc * 16 + wave * 4;

    // 256-wide step entirely in one segment: no weight select
#define STEP_U(VJ, XI, W)                                                     \
    {                                                                         \
        float dx;                                                             \
        dx = VJ.x - XI.x; acc = fmaf(dx * dx, (W), acc);                      \
        dx = VJ.y - XI.y; acc = fmaf(dx * dx, (W), acc);                      \
        dx = VJ.z - XI.z; acc = fmaf(dx * dx, (W), acc);                      \
        dx = VJ.w - XI.w; acc = fmaf(dx * dx, (W), acc);                      \
    }
    // 256-wide step crossing one boundary B: one cmp+select per element
    // (cmp operands identical across the 4 pairs -> CSE'd by the compiler)
#define STEP_B(T, VJ, XI, WLO, WHI, B)                                        \
    {                                                                         \
        const int k0 = ((T) * 64 + lane) * 4;                                 \
        float dx;                                                             \
        dx = VJ.x - XI.x; acc = fmaf(dx * dx, (k0 + 0 < (B)) ? (WLO) : (WHI), acc); \
        dx = VJ.y - XI.y; acc = fmaf(dx * dx, (k0 + 1 < (B)) ? (WLO) : (WHI), acc); \
        dx = VJ.z - XI.z; acc = fmaf(dx * dx, (k0 + 2 < (B)) ? (WLO) : (WHI), acc); \
        dx = VJ.w - XI.w; acc = fmaf(dx * dx, (k0 + 3 < (B)) ? (WLO) : (WHI), acc); \
    }

#define PAIR(ACCOUT, J)                                                       \
    {                                                                         \
        const float4* __restrict__ xjp = (const float4*)(x + (J) * 2048);     \
        const float* __restrict__ aw   = attr + (i * 64 + (J)) * 6;           \
        const float a20 = aw[0] * aw[0], a21 = aw[1] * aw[1],                 \
                    a22 = aw[2] * aw[2], a23 = aw[3] * aw[3],                 \
                    a24 = aw[4] * aw[4], a25 = aw[5] * aw[5];                 \
        float acc = 0.f;                                                      \
        float4 vj;                                                            \
        vj = xjp[0 * 64 + lane]; STEP_U(vj, xr0, a20);                        \
        vj = xjp[1 * 64 + lane]; STEP_B(1, vj, xr1, a20, a21, 341);           \
        vj = xjp[2 * 64 + lane]; STEP_B(2, vj, xr2, a21, a22, 682);           \
        vj = xjp[3 * 64 + lane]; STEP_B(3, vj, xr3, a22, a23, 1023);          \
        vj = xjp[4 * 64 + lane]; STEP_U(vj, xr4, a23);                        \
        vj = xjp[5 * 64 + lane]; STEP_B(5, vj, xr5, a23, a24, 1364);          \
        vj = xjp[6 * 64 + lane]; STEP_B(6, vj, xr6, a24, a25, 1705);          \
        vj = xjp[7 * 64 + lane]; STEP_U(vj, xr7, a25);                        \
        ACCOUT = acc;                                                         \
    }

    float acc0, acc1, acc2, acc3;
    PAIR(acc0, jbase + 0);
    PAIR(acc1, jbase + 1);
    PAIR(acc2, jbase + 2);
    PAIR(acc3, jbase + 3);
#undef PAIR
#undef STEP_B
#undef STEP_U

    // 64-lane butterfly sum per pair; lane 0 stores dist to LDS
#define REDW(ACC, Q)                                                          \
    {                                                                         \
        _Pragma("unroll")                                                     \
        for (int off = 32; off; off >>= 1) ACC += __shfl_xor(ACC, off);       \
        if (lane == 0) sm[wave * 4 + (Q)] = sqrtf(fmaxf(ACC, 1e-12f));        \
    }
    REDW(acc0, 0); REDW(acc1, 1); REDW(acc2, 2); REDW(acc3, 3);
#undef REDW

    __syncthreads();

    // 16-wide masked max/min by lanes 0..15 of wave 0 -> device-visible partial
    if (threadIdx.x < 16) {
        const int   j   = jc * 16 + threadIdx.x;
        const float d   = sm[threadIdx.x];
        const bool  pos = (tgt[j] == ti);
        float apv = pos ? d : -INFINITY;
        float anv = pos ? INFINITY : d;
#pragma unroll
        for (int off = 8; off; off >>= 1) {
            apv = fmaxf(apv, __shfl_xor(apv, off));
            anv = fminf(anv, __shfl_xor(anv, off));
        }
        if (threadIdx.x == 0) {
            // device-scope atomics: performed at the coherent point, visible
            // across XCDs once the counter increment is observed
            atomicExch(&ws[2 * b + 0], apv);
            atomicExch(&ws[2 * b + 1], anv);
            __threadfence();
            const int old = atomicAdd((int*)((char*)ws + 2048), 1);
            s_last = (old == 255) ? 1 : 0;
        }
    }
    __syncthreads();

    if (s_last) {
        __threadfence();  // acquire: see all blocks' partials
        if (threadIdx.x < 64) {
            const int r = threadIdx.x;
            float apv = -INFINITY, anv = INFINITY;
#pragma unroll
            for (int c = 0; c < 4; ++c) {
                const float2 v = *(const float2*)(ws + 2 * (r * 4 + c));
                apv = fmaxf(apv, v.x);
                anv = fminf(anv, v.y);
            }
            // an = +inf (no negatives) -> term = relu(-inf) = 0, matches ref
            float term = fmaxf(apv - anv + 0.3f, 0.f);
#pragma unroll
            for (int off = 32; off; off >>= 1) term += __shfl_xor(term, off);
            if (r == 0) out[0] = term * (1.0f / 64.0f);
        }
    }
}

extern "C" void kernel_launch(void* const* d_in, const int* in_sizes, int n_in,
                              void* d_out, int out_size, void* d_ws, size_t ws_size,
                              hipStream_t stream) {
    const float* x    = (const float*)d_in[0];   // inputs (64,2048) f32
    const int*   tgt  = (const int*)d_in[1];     // targets (64,) i32
    const float* attr = (const float*)d_in[2];   // attention (64,64,6) f32
    float* out = (float*)d_out;
    float* ws  = (float*)d_ws;

    // zero the arrival counter (byte offset 2048) each call — deterministic
    // across graph replays, and graph-capturable (async memset on stream)
    hipMemsetAsync((char*)d_ws + 2048, 0, 4, stream);
    triplet_fused<<<256, 256, 0, stream>>>(x, tgt, attr, out, ws);
}